// Round 1
// baseline (949.340 us; speedup 1.0000x reference)
//
#include <hip/hip_runtime.h>

// ---------------------------------------------------------------------------
// AttentiveDensenet on MI355X (gfx950), bf16-MFMA baseline.
// B=8, C=256, H=W=32 (HW=1024), L=4, NH=8, K=V=64, KH=VH=512, TOPK=4.
// ---------------------------------------------------------------------------

typedef __attribute__((ext_vector_type(8))) short short8;
typedef __attribute__((ext_vector_type(4))) float f32x4;

#define NTOK 65536   // B*HW*NH
#define NPIX 8192    // B*HW

__device__ __forceinline__ float bf2f(unsigned short u) {
  unsigned int v = ((unsigned int)u) << 16;
  float f; __builtin_memcpy(&f, &v, 4); return f;
}
__device__ __forceinline__ unsigned short f2bf(float f) {
  unsigned int u; __builtin_memcpy(&u, &f, 4);
  u = (u + 0x7FFFu + ((u >> 16) & 1u)) >> 16;
  return (unsigned short)u;
}

// ---------------------------------------------------------------------------
// init / cast kernels
// ---------------------------------------------------------------------------
__global__ void k_cast_x(const float* __restrict__ xin, float* __restrict__ xf,
                         unsigned short* __restrict__ xb, int n) {
  int i = blockIdx.x * 256 + threadIdx.x;
  if (i < n) { float v = xin[i]; xf[i] = v; xb[i] = f2bf(v); }
}

// kw/vw/qw f32 [L][512][256] -> wkqv bf16 [L][3][512][256], slot order k,v,q
__global__ void k_cast_kqv(const float* __restrict__ kw, const float* __restrict__ vw,
                           const float* __restrict__ qw, unsigned short* __restrict__ out) {
  int i = blockIdx.x * 256 + threadIdx.x;       // 4*3*512*256 = 1572864
  if (i >= 4 * 3 * 512 * 256) return;
  int idx = i & (131072 - 1);                   // within [512][256]
  int slotl = i >> 17;                          // l*3 + slot
  int slot = slotl % 3, l = slotl / 3;
  const float* s = (slot == 0) ? kw : (slot == 1) ? vw : qw;
  out[i] = f2bf(s[(size_t)l * 131072 + idx]);
}

// conv weights f32 [Mtot][CIN][9] -> bf16 [Mtot][9][CIN]   (Mtot = L*256)
__global__ void k_cast_reorder(const float* __restrict__ w, unsigned short* __restrict__ out,
                               int Mtot, int CIN) {
  int i = blockIdx.x * 256 + threadIdx.x;
  int total = Mtot * CIN * 9;
  if (i >= total) return;
  int c = i % CIN;
  int tap = (i / CIN) % 9;
  int m = i / (CIN * 9);
  out[i] = f2bf(w[((size_t)m * CIN + c) * 9 + tap]);
}

// kb/vb/qb f32 [L][512] -> biascat [L][3][512] (k,v,q)
__global__ void k_bias_cat(const float* __restrict__ kb, const float* __restrict__ vb,
                           const float* __restrict__ qb, float* __restrict__ out) {
  int i = blockIdx.x * 256 + threadIdx.x;       // 6144
  if (i >= 6144) return;
  int o = i & 511;
  int slotl = i >> 9;
  int slot = slotl % 3, l = slotl / 3;
  const float* s = (slot == 0) ? kb : (slot == 1) ? vb : qb;
  out[i] = s[l * 512 + o];
}

// ---------------------------------------------------------------------------
// MFMA GEMM: C[m][n] = sum_k A[m][k]*B[k][n] + bias[m]
//   A = W bf16 [Mtot][KDIM] row-major
//   B dense: act bf16 [B][KDIM][1024] ;  B conv: im2col of padded act
//            act bf16 [B][CIN][34*34], k = tap*CIN + c, tap = dy*3+dx
// 64x64 tile, 4 waves (2x2 of 32x32), K-step 32, mfma_f32_16x16x32_bf16.
// epi: 0 -> out_bf [B][Mtot][1024]; 1 -> out_f32; 2 -> xf32 += gamma*v, xbf=bf16
// ---------------------------------------------------------------------------
template<int KDIM, int CONV, int CIN>
__global__ __launch_bounds__(256) void k_gemm(
    const unsigned short* __restrict__ W,
    const unsigned short* __restrict__ act,
    const float* __restrict__ bias,
    int Mtot, int epi,
    unsigned short* __restrict__ out_bf,
    float* __restrict__ out_f32,
    float* __restrict__ xf32, unsigned short* __restrict__ xbf,
    const float* __restrict__ gamma_p) {
  __shared__ unsigned short As[64][40];   // [m][k], +8 pad
  __shared__ unsigned short Bs[64][40];   // [n][k], +8 pad

  const int tid = threadIdx.x;
  const int m0 = blockIdx.x * 64;
  const int hw0 = blockIdx.y * 64;
  const int b = blockIdx.z;

  const int arow = tid >> 2;              // A: 64 rows x 4 chunks of 8 k
  const int achk = (tid & 3) * 8;
  const int nn = tid & 63;                // B: 64 cols x 4 groups of 8 k
  const int kgrp = tid >> 6;
  const int n_glob = hw0 + nn;
  const int py = n_glob >> 5, px = n_glob & 31;

  const unsigned short* actb = act + (size_t)b * (CONV ? (size_t)CIN * 1156 : (size_t)KDIM * 1024);
  const unsigned short* wrow = W + (size_t)(m0 + arow) * KDIM + achk;

  const int wid = tid >> 6, lane = tid & 63;
  const int m_off = (wid >> 1) * 32, n_off = (wid & 1) * 32;
  const int lr = lane & 15, lg = lane >> 4;

  f32x4 acc00{}, acc01{}, acc10{}, acc11{};

  for (int k0 = 0; k0 < KDIM; k0 += 32) {
    short8 av = *(const short8*)(wrow + k0);
    short8 bv;
    if constexpr (CONV) {
      constexpr int CSH = (CIN == 512) ? 9 : 8;
      const int kb0 = k0 + kgrp * 8;
      const int tap = kb0 >> CSH;           // same tap for all 8 (CIN % 8 == 0)
      const int c0 = kb0 & (CIN - 1);
      const int dy = tap / 3, dx = tap - 3 * dy;
      const unsigned short* bp = actb + (size_t)c0 * 1156 + (py + dy) * 34 + (px + dx);
      #pragma unroll
      for (int i = 0; i < 8; i++) bv[i] = (short)bp[(size_t)i * 1156];
    } else {
      const unsigned short* bp = actb + (size_t)(k0 + kgrp * 8) * 1024 + n_glob;
      #pragma unroll
      for (int i = 0; i < 8; i++) bv[i] = (short)bp[(size_t)i * 1024];
    }
    __syncthreads();                        // LDS safe to overwrite
    *(short8*)&As[arow][achk] = av;
    *(short8*)&Bs[nn][kgrp * 8] = bv;
    __syncthreads();
    short8 a0 = *(const short8*)&As[m_off + lr][lg * 8];
    short8 a1 = *(const short8*)&As[m_off + 16 + lr][lg * 8];
    short8 b0 = *(const short8*)&Bs[n_off + lr][lg * 8];
    short8 b1 = *(const short8*)&Bs[n_off + 16 + lr][lg * 8];
    acc00 = __builtin_amdgcn_mfma_f32_16x16x32_bf16(a0, b0, acc00, 0, 0, 0);
    acc01 = __builtin_amdgcn_mfma_f32_16x16x32_bf16(a0, b1, acc01, 0, 0, 0);
    acc10 = __builtin_amdgcn_mfma_f32_16x16x32_bf16(a1, b0, acc10, 0, 0, 0);
    acc11 = __builtin_amdgcn_mfma_f32_16x16x32_bf16(a1, b1, acc11, 0, 0, 0);
  }

  const float gm = (epi == 2) ? gamma_p[0] : 0.0f;
  f32x4 accs[2][2] = {{acc00, acc01}, {acc10, acc11}};
  #pragma unroll
  for (int mi = 0; mi < 2; mi++) {
    #pragma unroll
    for (int r = 0; r < 4; r++) {
      const int m = m0 + m_off + mi * 16 + lg * 4 + r;   // D: row=(lane>>4)*4+reg
      const float bs = bias[m];
      #pragma unroll
      for (int ni = 0; ni < 2; ni++) {
        const int n = hw0 + n_off + ni * 16 + lr;        // D: col=lane&15
        const float v = accs[mi][ni][r] + bs;
        const size_t idx = ((size_t)b * Mtot + m) * 1024 + n;
        if (epi == 0) {
          out_bf[idx] = f2bf(v);
        } else if (epi == 1) {
          out_f32[idx] = v;
        } else {
          float xn = xf32[idx] + gm * v;
          xf32[idx] = xn;
          xbf[idx] = f2bf(xn);
        }
      }
    }
  }
}

// ---------------------------------------------------------------------------
// transpose: qkv chw bf16 [B][1536][1024] -> token-major [NTOK][64]
// grid (24 = tensor*8+head, 16 hw-tiles, 8 b), 256 threads
// ---------------------------------------------------------------------------
__global__ __launch_bounds__(256) void k_chw2tok(const unsigned short* __restrict__ src,
                                                 unsigned short* __restrict__ k_tok,
                                                 unsigned short* __restrict__ v_tok,
                                                 unsigned short* __restrict__ q_tok, int l) {
  __shared__ unsigned short t[64][65];
  const int hg = blockIdx.x;
  const int tensor = hg >> 3, head = hg & 7;
  const int hw0 = blockIdx.y * 64, b = blockIdx.z;
  const int tid = threadIdx.x;
  {
    const int j = tid >> 2, chk = (tid & 3) * 16;
    const unsigned short* sp = src + ((size_t)b * 1536 + tensor * 512 + head * 64 + j) * 1024 + hw0 + chk;
    #pragma unroll
    for (int i = 0; i < 16; i++) t[j][chk + i] = sp[i];
  }
  __syncthreads();
  unsigned short* dst = (tensor == 0) ? (k_tok + (size_t)l * NTOK * 64)
                      : (tensor == 1) ? (v_tok + (size_t)l * NTOK * 64)
                                      : q_tok;
  const int xl = tid >> 2, chk = (tid & 3) * 16;
  const size_t token = ((size_t)b * 1024 + hw0 + xl) * 8 + head;
  unsigned short* dp = dst + token * 64 + chk;
  #pragma unroll
  for (int i = 0; i < 16; i++) dp[i] = t[chk + i][xl];
}

// ---------------------------------------------------------------------------
// attention: 1 wave per token (lane = dim), o_tok bf16 [NTOK][64]
// ---------------------------------------------------------------------------
__global__ __launch_bounds__(256) void k_attn(const unsigned short* __restrict__ q_tok,
                                              const unsigned short* __restrict__ k_tok,
                                              const unsigned short* __restrict__ v_tok,
                                              unsigned short* __restrict__ o_tok, int l) {
  const int wid = threadIdx.x >> 6, lane = threadIdx.x & 63;
  const size_t token = (size_t)blockIdx.x * 4 + wid;
  const float qv = bf2f(q_tok[token * 64 + lane]) * 0.125f;   // / sqrt(64)
  float s[5];
  const int T = l + 2;
  for (int t = 0; t <= l; t++) {
    float p = qv * bf2f(k_tok[(size_t)t * NTOK * 64 + token * 64 + lane]);
    #pragma unroll
    for (int off = 32; off > 0; off >>= 1) p += __shfl_xor(p, off);
    s[t] = p;
  }
  s[l + 1] = 0.0f;                 // zero key -> score exactly 0
  float mx = s[0];
  for (int t = 1; t < T; t++) mx = fmaxf(mx, s[t]);
  float e[5], sum = 0.0f;
  for (int t = 0; t < T; t++) { e[t] = __expf(s[t] - mx); sum += e[t]; }
  const float inv = 1.0f / sum;
  float attn[5];
  for (int t = 0; t < T; t++) attn[t] = e[t] * inv;
  if (T == 5) {                    // SparseAttention top-4 threshold (layer 3)
    float a[5];
    #pragma unroll
    for (int t = 0; t < 5; t++) a[t] = attn[t];
    #pragma unroll
    for (int i = 0; i < 4; i++)
      #pragma unroll
      for (int j = 0; j < 4; j++)
        if (a[j] < a[j + 1]) { float tmp = a[j]; a[j] = a[j + 1]; a[j + 1] = tmp; }
    const float delta = a[3] + 1e-7f;
    float wsum = 0.0f;
    #pragma unroll
    for (int t = 0; t < 5; t++) { attn[t] = fmaxf(attn[t] - delta, 0.0f); wsum += attn[t]; }
    const float r = 1.0f / (wsum + 1e-7f);
    #pragma unroll
    for (int t = 0; t < 5; t++) attn[t] *= r;
  }
  float o = 0.0f;
  for (int t = 0; t <= l; t++) o += attn[t] * bf2f(v_tok[(size_t)t * NTOK * 64 + token * 64 + lane]);
  o_tok[token * 64 + lane] = f2bf(o);
}

// ---------------------------------------------------------------------------
// o token-major -> padded chw bf16 [B][512][34][34] (interior; borders pre-zeroed)
// grid (8 heads, 16 hw-tiles, 8 b)
// ---------------------------------------------------------------------------
__global__ __launch_bounds__(256) void k_tok2pad(const unsigned short* __restrict__ o_tok,
                                                 unsigned short* __restrict__ opad) {
  __shared__ unsigned short t[64][65];
  const int head = blockIdx.x;
  const int hw0 = blockIdx.y * 64, b = blockIdx.z;
  const int tid = threadIdx.x;
  {
    const int xl = tid >> 2, chk = (tid & 3) * 16;
    const size_t token = ((size_t)b * 1024 + hw0 + xl) * 8 + head;
    const unsigned short* sp = o_tok + token * 64 + chk;
    #pragma unroll
    for (int i = 0; i < 16; i++) t[xl][chk + i] = sp[i];
  }
  __syncthreads();
  const int j = tid >> 2, chk = (tid & 3) * 16;
  const int ch = head * 64 + j;
  const int hwb = hw0 + chk;                       // 16-chunk stays in one image row
  const int y = hwb >> 5, x0 = hwb & 31;
  unsigned short* dp = opad + ((size_t)b * 512 + ch) * 1156 + (y + 1) * 34 + (x0 + 1);
  #pragma unroll
  for (int i = 0; i < 16; i++) dp[i] = t[chk + i][j];
}

// ---------------------------------------------------------------------------
// BN train-mode stats over (B,H,W) per channel; stats[c] = g*rsqrt(var+eps),
// stats[256+c] = beta - mean*scale
// ---------------------------------------------------------------------------
__global__ __launch_bounds__(256) void k_bn_stats(const float* __restrict__ h,
                                                  const float* __restrict__ g,
                                                  const float* __restrict__ bta,
                                                  float* __restrict__ stats, int l) {
  const int c = blockIdx.x, tid = threadIdx.x;
  float s = 0.0f, ss = 0.0f;
  for (int i = tid; i < 8192; i += 256) {
    const int b = i >> 10, pos = i & 1023;
    const float v = h[((size_t)b * 256 + c) * 1024 + pos];
    s += v; ss += v * v;
  }
  #pragma unroll
  for (int off = 32; off > 0; off >>= 1) { s += __shfl_xor(s, off); ss += __shfl_xor(ss, off); }
  __shared__ float rs[4], rss[4];
  const int wid = tid >> 6, lane = tid & 63;
  if (lane == 0) { rs[wid] = s; rss[wid] = ss; }
  __syncthreads();
  if (tid == 0) {
    const float S = rs[0] + rs[1] + rs[2] + rs[3];
    const float SS = rss[0] + rss[1] + rss[2] + rss[3];
    const float m = S * (1.0f / 8192.0f);
    const float var = SS * (1.0f / 8192.0f) - m * m;
    const float A = g[l * 256 + c] * rsqrtf(var + 1e-5f);
    stats[c] = A;
    stats[256 + c] = bta[l * 256 + c] - m * A;
  }
}

// BN apply + ReLU + write padded bf16 [B][256][34][34] interior
__global__ void k_bn_relu_pad(const float* __restrict__ h, const float* __restrict__ stats,
                              unsigned short* __restrict__ hpad) {
  const int i = blockIdx.x * 256 + threadIdx.x;   // (b*256+c)*1024 + hw
  if (i >= NPIX * 256) return;
  const int hw = i & 1023;
  const int c = (i >> 10) & 255;
  const int bc = i >> 10;
  float v = h[i] * stats[c] + stats[256 + c];
  v = fmaxf(v, 0.0f);
  const int y = hw >> 5, x = hw & 31;
  hpad[(size_t)bc * 1156 + (y + 1) * 34 + (x + 1)] = f2bf(v);
}

// ---------------------------------------------------------------------------
extern "C" void kernel_launch(void* const* d_in, const int* in_sizes, int n_in,
                              void* d_out, int out_size, void* d_ws, size_t ws_size,
                              hipStream_t stream) {
  (void)in_sizes; (void)n_in; (void)out_size;
  const float* x_in   = (const float*)d_in[0];
  const float* kw     = (const float*)d_in[1];
  const float* kb     = (const float*)d_in[2];
  const float* qw     = (const float*)d_in[3];
  const float* qb     = (const float*)d_in[4];
  const float* vw     = (const float*)d_in[5];
  const float* vb     = (const float*)d_in[6];
  const float* ow1    = (const float*)d_in[7];
  const float* ob1    = (const float*)d_in[8];
  const float* bn_g   = (const float*)d_in[9];
  const float* bn_b   = (const float*)d_in[10];
  const float* ow2    = (const float*)d_in[11];
  const float* ob2    = (const float*)d_in[12];
  const float* gammas = (const float*)d_in[13];

  char* ws = (char*)d_ws;
  size_t off = 0;
  auto alloc = [&](size_t bytes) -> void* {
    void* p = ws + off;
    off += (bytes + 255) & ~(size_t)255;
    return p;
  };
  float*          xf32    = (float*)alloc((size_t)NPIX * 256 * 4);
  unsigned short* xbf     = (unsigned short*)alloc((size_t)NPIX * 256 * 2);
  unsigned short* tmp_chw = (unsigned short*)alloc((size_t)NPIX * 1536 * 2);
  unsigned short* k_tok   = (unsigned short*)alloc((size_t)4 * NTOK * 64 * 2);
  unsigned short* v_tok   = (unsigned short*)alloc((size_t)4 * NTOK * 64 * 2);
  unsigned short* q_tok   = (unsigned short*)alloc((size_t)NTOK * 64 * 2);
  unsigned short* o_tok   = (unsigned short*)alloc((size_t)NTOK * 64 * 2);
  unsigned short* opad    = (unsigned short*)alloc((size_t)8 * 512 * 1156 * 2);
  float*          h1raw   = (float*)alloc((size_t)NPIX * 256 * 4);
  unsigned short* h1pad   = (unsigned short*)alloc((size_t)8 * 256 * 1156 * 2);
  float*          stats   = (float*)alloc(512 * 4);
  unsigned short* wkqv    = (unsigned short*)alloc((size_t)4 * 3 * 512 * 256 * 2);
  unsigned short* w1bf    = (unsigned short*)alloc((size_t)1024 * 4608 * 2);
  unsigned short* w2bf    = (unsigned short*)alloc((size_t)1024 * 2304 * 2);
  float*          biascat = (float*)alloc((size_t)6144 * 4);
  if (off > ws_size) return;  // insufficient scratch — fail loudly at validation

  // --- init: pads zeroed once (interiors rewritten each layer) ---
  hipMemsetAsync(opad, 0, (size_t)8 * 512 * 1156 * 2, stream);
  hipMemsetAsync(h1pad, 0, (size_t)8 * 256 * 1156 * 2, stream);
  k_cast_x<<<NPIX, 256, 0, stream>>>(x_in, xf32, xbf, NPIX * 256);
  k_cast_kqv<<<6144, 256, 0, stream>>>(kw, vw, qw, wkqv);
  k_cast_reorder<<<18432, 256, 0, stream>>>(ow1, w1bf, 1024, 512);
  k_cast_reorder<<<9216, 256, 0, stream>>>(ow2, w2bf, 1024, 256);
  k_bias_cat<<<24, 256, 0, stream>>>(kb, vb, qb, biascat);

  for (int l = 0; l < 4; l++) {
    // QKV: [1536][256] x [256][1024] per batch -> tmp_chw bf16
    k_gemm<256, 0, 256><<<dim3(24, 16, 8), 256, 0, stream>>>(
        wkqv + (size_t)l * 3 * 512 * 256, xbf, biascat + l * 1536, 1536, 0,
        tmp_chw, nullptr, nullptr, nullptr, nullptr);
    k_chw2tok<<<dim3(24, 16, 8), 256, 0, stream>>>(tmp_chw, k_tok, v_tok, q_tok, l);
    k_attn<<<NTOK / 4, 256, 0, stream>>>(q_tok, k_tok, v_tok, o_tok, l);
    k_tok2pad<<<dim3(8, 16, 8), 256, 0, stream>>>(o_tok, opad);
    // conv3x3 #1: 512 -> 256, K = 4608, f32 out for BN stats
    k_gemm<4608, 1, 512><<<dim3(4, 16, 8), 256, 0, stream>>>(
        w1bf + (size_t)l * 256 * 4608, opad, ob1 + l * 256, 256, 1,
        nullptr, h1raw, nullptr, nullptr, nullptr);
    k_bn_stats<<<256, 256, 0, stream>>>(h1raw, bn_g, bn_b, stats, l);
    k_bn_relu_pad<<<NPIX, 256, 0, stream>>>(h1raw, stats, h1pad);
    // conv3x3 #2: 256 -> 256, K = 2304, fused residual x += gamma*h2
    k_gemm<2304, 1, 256><<<dim3(4, 16, 8), 256, 0, stream>>>(
        w2bf + (size_t)l * 256 * 2304, h1pad, ob2 + l * 256, 256, 2,
        nullptr, nullptr, xf32, xbf, gammas + l);
  }
  hipMemcpyAsync(d_out, xf32, (size_t)NPIX * 256 * 4, hipMemcpyDeviceToDevice, stream);
}

// Round 2
// 680.783 us; speedup vs baseline: 1.3945x; 1.3945x over previous
//
#include <hip/hip_runtime.h>

// ---------------------------------------------------------------------------
// AttentiveDensenet on MI355X (gfx950) — round 2: channel-last activations,
// XCD-grouped GEMM blocks, register prefetch, XOR-swizzled LDS, K-step 64.
// B=8, C=256, H=W=32 (HW=1024), L=4, NH=8, K=V=64.
// ---------------------------------------------------------------------------

typedef __attribute__((ext_vector_type(8))) short short8;
typedef __attribute__((ext_vector_type(4))) float f32x4;
typedef __attribute__((ext_vector_type(4))) unsigned short ushort4_t;

#define NTOK 65536   // B*HW*NH
#define NPIX 8192    // B*HW

__device__ __forceinline__ float bf2f(unsigned short u) {
  unsigned int v = ((unsigned int)u) << 16;
  float f; __builtin_memcpy(&f, &v, 4); return f;
}
__device__ __forceinline__ unsigned short f2bf(float f) {
  unsigned int u; __builtin_memcpy(&u, &f, 4);
  u = (u + 0x7FFFu + ((u >> 16) & 1u)) >> 16;
  return (unsigned short)u;
}

// ---------------------------------------------------------------------------
// weight prep (unchanged layouts: A rows contiguous in k = tap*CIN + c)
// ---------------------------------------------------------------------------
__global__ void k_cast_kqv(const float* __restrict__ kw, const float* __restrict__ vw,
                           const float* __restrict__ qw, unsigned short* __restrict__ out) {
  int i = blockIdx.x * 256 + threadIdx.x;       // 4*3*512*256
  if (i >= 4 * 3 * 512 * 256) return;
  int idx = i & (131072 - 1);
  int slotl = i >> 17;
  int slot = slotl % 3, l = slotl / 3;
  const float* s = (slot == 0) ? kw : (slot == 1) ? vw : qw;
  out[i] = f2bf(s[(size_t)l * 131072 + idx]);
}

__global__ void k_cast_reorder(const float* __restrict__ w, unsigned short* __restrict__ out,
                               int Mtot, int CIN) {
  int i = blockIdx.x * 256 + threadIdx.x;
  int total = Mtot * CIN * 9;
  if (i >= total) return;
  int c = i % CIN;
  int tap = (i / CIN) % 9;
  int m = i / (CIN * 9);
  out[i] = f2bf(w[((size_t)m * CIN + c) * 9 + tap]);
}

__global__ void k_bias_cat(const float* __restrict__ kb, const float* __restrict__ vb,
                           const float* __restrict__ qb, float* __restrict__ out) {
  int i = blockIdx.x * 256 + threadIdx.x;       // 6144
  if (i >= 6144) return;
  int o = i & 511;
  int slotl = i >> 9;
  int slot = slotl % 3, l = slotl / 3;
  const float* s = (slot == 0) ? kb : (slot == 1) ? vb : qb;
  out[i] = s[l * 512 + o];
}

// ---------------------------------------------------------------------------
// x (f32, [B][256][1024] c-major) -> xcl (bf16, [B][1024][256] pixel-major)
// ---------------------------------------------------------------------------
__global__ __launch_bounds__(256) void k_x2cl(const float* __restrict__ src,
                                              unsigned short* __restrict__ dst) {
  __shared__ unsigned short t[64][68];
  const int hw0 = blockIdx.x * 64, b = blockIdx.y;
  const int tid = threadIdx.x;
  for (int cc = 0; cc < 4; cc++) {
    __syncthreads();
    {
      const int px = tid & 63, c = tid >> 6;
      #pragma unroll
      for (int i = 0; i < 16; i++)
        t[px][c + i * 4] = f2bf(src[((size_t)b * 256 + cc * 64 + c + i * 4) * 1024 + hw0 + px]);
    }
    __syncthreads();
    {
      const int px = tid >> 2, c0 = (tid & 3) * 16;
      unsigned short* dp = dst + ((size_t)b * 1024 + hw0 + px) * 256 + cc * 64 + c0;
      short8 v0, v1;
      #pragma unroll
      for (int i = 0; i < 8; i++) { v0[i] = (short)t[px][c0 + i]; v1[i] = (short)t[px][c0 + 8 + i]; }
      *(short8*)dp = v0; *(short8*)(dp + 8) = v1;
    }
  }
}

// ---------------------------------------------------------------------------
// MFMA GEMM v2. Tile 64x64, 4 waves (2x2 of 32x32), K-step 64, reg prefetch,
// XOR chunk-swizzled LDS (rows 128B, chunk ^= row&7), XCD-grouped blocks.
//   A = W bf16 [Mtot][KDIM] row-major, k = tap*CIN + c for conv.
//   B conv: padded channel-last act [B][34*34][CIN]; dense: [B][1024][CIN].
// epi 0: token-major QKV out; 1: h1raw f32 [B][256][1024]; 2: d_out += g*v.
// ---------------------------------------------------------------------------
template<int KDIM, int CONV, int CIN, int MT>
__global__ __launch_bounds__(256) void k_gemm(
    const unsigned short* __restrict__ W,
    const unsigned short* __restrict__ act,
    const float* __restrict__ bias,
    int epi, int l,
    unsigned short* __restrict__ ktok, unsigned short* __restrict__ vtok,
    unsigned short* __restrict__ qtok,
    float* __restrict__ out_f32,
    const float* __restrict__ gamma_p) {
  __shared__ unsigned short As[64 * 64];
  __shared__ unsigned short Bs[64 * 64];

  // XCD-grouped decode: all MT m-tiles of one (hw,b) group land on one XCD.
  const int bid = blockIdx.x;                 // MT*128 blocks total
  const int xcd = bid & 7, li = bid >> 3;     // assume round-robin dispatch
  const int g = xcd * 16 + li / MT;           // 0..127 -> (b, hw-tile)
  const int mt = li % MT;
  const int b = g >> 4, hwt = g & 15;
  const int m0 = mt * 64, hw0 = hwt * 64;

  const int tid = threadIdx.x;
  const int wid = tid >> 6, lane = tid & 63;
  const int lr = lane & 15, lg = lane >> 4;
  const int m_off = (wid >> 1) * 32, n_off = (wid & 1) * 32;

  // staging assignments
  const int arow = tid >> 2, apair = tid & 3;   // A: 64 rows x 2 chunks @ apair*16
  const int nn = tid & 63, kgrp = tid >> 6;     // B: 64 cols x 2 chunks @ kgrp*16
  const int n_glob = hw0 + nn;
  const int py = n_glob >> 5, px = n_glob & 31;
  const unsigned short* wrow = W + (size_t)(m0 + arow) * KDIM + apair * 16;
  const unsigned short* actb = act + (size_t)b * (CONV ? (size_t)1156 * CIN : (size_t)1024 * CIN);
  const unsigned short* actpix = actb + (size_t)n_glob * CIN;   // dense path

  // LDS write offsets (shorts), chunk-swizzled
  const int aw0 = arow * 64 + (((apair * 2    ) ^ (arow & 7)) * 8);
  const int aw1 = arow * 64 + (((apair * 2 + 1) ^ (arow & 7)) * 8);
  const int bw0 = nn * 64 + (((kgrp * 2    ) ^ (nn & 7)) * 8);
  const int bw1 = nn * 64 + (((kgrp * 2 + 1) ^ (nn & 7)) * 8);
  // LDS read offsets: frag (mi/ni, ks) -> row, chunk ks*4+lg
  int ard[2][2], brd[2][2];
  #pragma unroll
  for (int i = 0; i < 2; i++)
    #pragma unroll
    for (int ks = 0; ks < 2; ks++) {
      const int ra = m_off + i * 16 + lr;
      ard[i][ks] = ra * 64 + (((ks * 4 + lg) ^ (ra & 7)) * 8);
      const int rb = n_off + i * 16 + lr;
      brd[i][ks] = rb * 64 + (((ks * 4 + lg) ^ (rb & 7)) * 8);
    }

  f32x4 acc[2][2] = {};
  short8 av0, av1, bv0, bv1;

  auto loadA = [&](int k0) {
    av0 = *(const short8*)(wrow + k0);
    av1 = *(const short8*)(wrow + k0 + 8);
  };
  auto loadB = [&](int k0) {
    if constexpr (CONV) {
      const int k = k0 + kgrp * 16;
      const int tap = k >> (CIN == 512 ? 9 : 8);
      const int c0 = k & (CIN - 1);
      const int dy = tap / 3, dx = tap - dy * 3;
      const unsigned short* bp = actb + ((size_t)(py + dy) * 34 + (px + dx)) * CIN + c0;
      bv0 = *(const short8*)bp; bv1 = *(const short8*)(bp + 8);
    } else {
      const unsigned short* bp = actpix + k0 + kgrp * 16;
      bv0 = *(const short8*)bp; bv1 = *(const short8*)(bp + 8);
    }
  };

  loadA(0); loadB(0);
  for (int k0 = 0; k0 < KDIM; k0 += 64) {
    __syncthreads();
    *(short8*)&As[aw0] = av0; *(short8*)&As[aw1] = av1;
    *(short8*)&Bs[bw0] = bv0; *(short8*)&Bs[bw1] = bv1;
    __syncthreads();
    if (k0 + 64 < KDIM) { loadA(k0 + 64); loadB(k0 + 64); }   // prefetch in flight over MFMA
    #pragma unroll
    for (int ks = 0; ks < 2; ks++) {
      short8 a0 = *(const short8*)&As[ard[0][ks]];
      short8 a1 = *(const short8*)&As[ard[1][ks]];
      short8 b0 = *(const short8*)&Bs[brd[0][ks]];
      short8 b1 = *(const short8*)&Bs[brd[1][ks]];
      acc[0][0] = __builtin_amdgcn_mfma_f32_16x16x32_bf16(a0, b0, acc[0][0], 0, 0, 0);
      acc[0][1] = __builtin_amdgcn_mfma_f32_16x16x32_bf16(a0, b1, acc[0][1], 0, 0, 0);
      acc[1][0] = __builtin_amdgcn_mfma_f32_16x16x32_bf16(a1, b0, acc[1][0], 0, 0, 0);
      acc[1][1] = __builtin_amdgcn_mfma_f32_16x16x32_bf16(a1, b1, acc[1][1], 0, 0, 0);
    }
  }

  const float gm = (epi == 2) ? gamma_p[0] : 0.0f;
  #pragma unroll
  for (int mi = 0; mi < 2; mi++) {
    const int mb = m0 + m_off + mi * 16 + lg * 4;     // 4 consecutive rows (r)
    float bs[4];
    #pragma unroll
    for (int r = 0; r < 4; r++) bs[r] = bias[mb + r];
    #pragma unroll
    for (int ni = 0; ni < 2; ni++) {
      const int n = hw0 + n_off + ni * 16 + lr;
      if (epi == 0) {
        const int tensor = mb >> 9, head = (mb >> 6) & 7, d0 = mb & 63;
        unsigned short* dst = (tensor == 0) ? ktok + (size_t)l * NTOK * 64
                            : (tensor == 1) ? vtok + (size_t)l * NTOK * 64 : qtok;
        ushort4_t pk;
        #pragma unroll
        for (int r = 0; r < 4; r++) pk[r] = f2bf(acc[mi][ni][r] + bs[r]);
        *(ushort4_t*)&dst[(((size_t)b * 1024 + n) * 8 + head) * 64 + d0] = pk;
      } else if (epi == 1) {
        #pragma unroll
        for (int r = 0; r < 4; r++)
          out_f32[((size_t)b * 256 + mb + r) * 1024 + n] = acc[mi][ni][r] + bs[r];
      } else {
        #pragma unroll
        for (int r = 0; r < 4; r++) {
          const size_t idx = ((size_t)b * 256 + mb + r) * 1024 + n;
          out_f32[idx] += gm * (acc[mi][ni][r] + bs[r]);
        }
      }
    }
  }
}

// ---------------------------------------------------------------------------
// attention: 1 wave per token (lane = dim); writes opad_cl interior directly
// ---------------------------------------------------------------------------
__global__ __launch_bounds__(256) void k_attn(const unsigned short* __restrict__ q_tok,
                                              const unsigned short* __restrict__ k_tok,
                                              const unsigned short* __restrict__ v_tok,
                                              unsigned short* __restrict__ opad, int l) {
  const int wid = threadIdx.x >> 6, lane = threadIdx.x & 63;
  const size_t token = (size_t)blockIdx.x * 4 + wid;
  const float qv = bf2f(q_tok[token * 64 + lane]) * 0.125f;   // / sqrt(64)
  float s[5];
  const int T = l + 2;
  for (int t = 0; t <= l; t++) {
    float p = qv * bf2f(k_tok[(size_t)t * NTOK * 64 + token * 64 + lane]);
    #pragma unroll
    for (int off = 32; off > 0; off >>= 1) p += __shfl_xor(p, off);
    s[t] = p;
  }
  s[l + 1] = 0.0f;
  float mx = s[0];
  for (int t = 1; t < T; t++) mx = fmaxf(mx, s[t]);
  float e[5], sum = 0.0f;
  for (int t = 0; t < T; t++) { e[t] = __expf(s[t] - mx); sum += e[t]; }
  const float inv = 1.0f / sum;
  float attn[5];
  for (int t = 0; t < T; t++) attn[t] = e[t] * inv;
  if (T == 5) {                    // SparseAttention top-4 (layer 3)
    float a[5];
    #pragma unroll
    for (int t = 0; t < 5; t++) a[t] = attn[t];
    #pragma unroll
    for (int i = 0; i < 4; i++)
      #pragma unroll
      for (int j = 0; j < 4; j++)
        if (a[j] < a[j + 1]) { float tmp = a[j]; a[j] = a[j + 1]; a[j + 1] = tmp; }
    const float delta = a[3] + 1e-7f;
    float wsum = 0.0f;
    #pragma unroll
    for (int t = 0; t < 5; t++) { attn[t] = fmaxf(attn[t] - delta, 0.0f); wsum += attn[t]; }
    const float r = 1.0f / (wsum + 1e-7f);
    #pragma unroll
    for (int t = 0; t < 5; t++) attn[t] *= r;
  }
  float o = 0.0f;
  for (int t = 0; t <= l; t++) o += attn[t] * bf2f(v_tok[(size_t)t * NTOK * 64 + token * 64 + lane]);
  const int head = (int)(token & 7), pix = (int)(token >> 3);
  const int b = pix >> 10, hw = pix & 1023, y = hw >> 5, x = hw & 31;
  opad[((size_t)b * 1156 + (y + 1) * 34 + (x + 1)) * 512 + head * 64 + lane] = f2bf(o);
}

// ---------------------------------------------------------------------------
// BN stats (h1raw is c-major): stats[c]=g*rsqrt(var+eps), stats[256+c]=b-m*A
// ---------------------------------------------------------------------------
__global__ __launch_bounds__(256) void k_bn_stats(const float* __restrict__ h,
                                                  const float* __restrict__ g,
                                                  const float* __restrict__ bta,
                                                  float* __restrict__ stats, int l) {
  const int c = blockIdx.x, tid = threadIdx.x;
  float s = 0.0f, ss = 0.0f;
  for (int i = tid; i < 8192; i += 256) {
    const int b = i >> 10, pos = i & 1023;
    const float v = h[((size_t)b * 256 + c) * 1024 + pos];
    s += v; ss += v * v;
  }
  #pragma unroll
  for (int off = 32; off > 0; off >>= 1) { s += __shfl_xor(s, off); ss += __shfl_xor(ss, off); }
  __shared__ float rs[4], rss[4];
  const int wid = tid >> 6, lane = tid & 63;
  if (lane == 0) { rs[wid] = s; rss[wid] = ss; }
  __syncthreads();
  if (tid == 0) {
    const float S = rs[0] + rs[1] + rs[2] + rs[3];
    const float SS = rss[0] + rss[1] + rss[2] + rss[3];
    const float m = S * (1.0f / 8192.0f);
    const float var = SS * (1.0f / 8192.0f) - m * m;
    const float A = g[l * 256 + c] * rsqrtf(var + 1e-5f);
    stats[c] = A;
    stats[256 + c] = bta[l * 256 + c] - m * A;
  }
}

// BN apply + ReLU -> padded channel-last bf16 [B][34*34][256] interior
__global__ __launch_bounds__(256) void k_bn_relu_pad_cl(const float* __restrict__ h,
    const float* __restrict__ stats, unsigned short* __restrict__ hpad) {
  __shared__ unsigned short t[64][68];
  const int hw0 = blockIdx.x * 64, b = blockIdx.y;
  const int tid = threadIdx.x;
  for (int cc = 0; cc < 4; cc++) {
    __syncthreads();
    {
      const int px = tid & 63, c = tid >> 6;
      #pragma unroll
      for (int i = 0; i < 16; i++) {
        const int ch = cc * 64 + c + i * 4;
        float v = h[((size_t)b * 256 + ch) * 1024 + hw0 + px] * stats[ch] + stats[256 + ch];
        t[px][c + i * 4] = f2bf(fmaxf(v, 0.0f));
      }
    }
    __syncthreads();
    {
      const int px = tid >> 2, c0 = (tid & 3) * 16;
      const int hw = hw0 + px, y = hw >> 5, x = hw & 31;
      unsigned short* dp = hpad + ((size_t)b * 1156 + (y + 1) * 34 + (x + 1)) * 256 + cc * 64 + c0;
      short8 v0, v1;
      #pragma unroll
      for (int i = 0; i < 8; i++) { v0[i] = (short)t[px][c0 + i]; v1[i] = (short)t[px][c0 + 8 + i]; }
      *(short8*)dp = v0; *(short8*)(dp + 8) = v1;
    }
  }
}

// ---------------------------------------------------------------------------
extern "C" void kernel_launch(void* const* d_in, const int* in_sizes, int n_in,
                              void* d_out, int out_size, void* d_ws, size_t ws_size,
                              hipStream_t stream) {
  (void)in_sizes; (void)n_in; (void)out_size;
  const float* x_in   = (const float*)d_in[0];
  const float* kw     = (const float*)d_in[1];
  const float* kb     = (const float*)d_in[2];
  const float* qw     = (const float*)d_in[3];
  const float* qb     = (const float*)d_in[4];
  const float* vw     = (const float*)d_in[5];
  const float* vb     = (const float*)d_in[6];
  const float* ow1    = (const float*)d_in[7];
  const float* ob1    = (const float*)d_in[8];
  const float* bn_g   = (const float*)d_in[9];
  const float* bn_b   = (const float*)d_in[10];
  const float* ow2    = (const float*)d_in[11];
  const float* ob2    = (const float*)d_in[12];
  const float* gammas = (const float*)d_in[13];

  char* ws = (char*)d_ws;
  size_t off = 0;
  auto alloc = [&](size_t bytes) -> void* {
    void* p = ws + off;
    off += (bytes + 255) & ~(size_t)255;
    return p;
  };
  unsigned short* xcl     = (unsigned short*)alloc((size_t)NPIX * 256 * 2);
  unsigned short* k_tok   = (unsigned short*)alloc((size_t)4 * NTOK * 64 * 2);
  unsigned short* v_tok   = (unsigned short*)alloc((size_t)4 * NTOK * 64 * 2);
  unsigned short* q_tok   = (unsigned short*)alloc((size_t)NTOK * 64 * 2);
  unsigned short* opad    = (unsigned short*)alloc((size_t)8 * 1156 * 512 * 2);
  float*          h1raw   = (float*)alloc((size_t)NPIX * 256 * 4);
  unsigned short* h1pad   = (unsigned short*)alloc((size_t)8 * 1156 * 256 * 2);
  float*          stats   = (float*)alloc(512 * 4);
  unsigned short* wkqv    = (unsigned short*)alloc((size_t)4 * 3 * 512 * 256 * 2);
  unsigned short* w1bf    = (unsigned short*)alloc((size_t)1024 * 4608 * 2);
  unsigned short* w2bf    = (unsigned short*)alloc((size_t)1024 * 2304 * 2);
  float*          biascat = (float*)alloc((size_t)6144 * 4);
  if (off > ws_size) return;  // insufficient scratch — fail loudly at validation

  float* xacc = (float*)d_out;   // f32 accumulator lives in d_out

  hipMemsetAsync(opad, 0, (size_t)8 * 1156 * 512 * 2, stream);
  hipMemsetAsync(h1pad, 0, (size_t)8 * 1156 * 256 * 2, stream);
  hipMemcpyAsync(xacc, x_in, (size_t)NPIX * 256 * 4, hipMemcpyDeviceToDevice, stream);
  k_x2cl<<<dim3(16, 8), 256, 0, stream>>>(x_in, xcl);
  k_cast_kqv<<<6144, 256, 0, stream>>>(kw, vw, qw, wkqv);
  k_cast_reorder<<<18432, 256, 0, stream>>>(ow1, w1bf, 1024, 512);
  k_cast_reorder<<<9216, 256, 0, stream>>>(ow2, w2bf, 1024, 256);
  k_bias_cat<<<24, 256, 0, stream>>>(kb, vb, qb, biascat);

  for (int l = 0; l < 4; l++) {
    // QKV: [1536][256] x [256 x 8192] -> token-major k/v/q directly
    k_gemm<256, 0, 256, 24><<<24 * 128, 256, 0, stream>>>(
        wkqv + (size_t)l * 3 * 512 * 256, xcl, biascat + l * 1536, 0, l,
        k_tok, v_tok, q_tok, nullptr, nullptr);
    k_attn<<<NTOK / 4, 256, 0, stream>>>(q_tok, k_tok, v_tok, opad, l);
    // conv3x3 #1: 512 -> 256 (K=4608), f32 out for BN
    k_gemm<4608, 1, 512, 4><<<4 * 128, 256, 0, stream>>>(
        w1bf + (size_t)l * 256 * 4608, opad, ob1 + l * 256, 1, l,
        nullptr, nullptr, nullptr, h1raw, nullptr);
    k_bn_stats<<<256, 256, 0, stream>>>(h1raw, bn_g, bn_b, stats, l);
    k_bn_relu_pad_cl<<<dim3(16, 8), 256, 0, stream>>>(h1raw, stats, h1pad);
    // conv3x3 #2: 256 -> 256 (K=2304), fused residual into d_out
    k_gemm<2304, 1, 256, 4><<<4 * 128, 256, 0, stream>>>(
        w2bf + (size_t)l * 256 * 2304, h1pad, ob2 + l * 256, 2, l,
        nullptr, nullptr, nullptr, xacc, gammas + l);
    if (l < 3) k_x2cl<<<dim3(16, 8), 256, 0, stream>>>(xacc, xcl);
  }
}

// Round 3
// 494.679 us; speedup vs baseline: 1.9191x; 1.3762x over previous
//
#include <hip/hip_runtime.h>

// ---------------------------------------------------------------------------
// AttentiveDensenet on MI355X (gfx950) — round 3: 128x128 tiles + split-K,
// global_load_lds(16B) staging, 1 barrier/K-step, fused combine epilogues.
// B=8, C=256, H=W=32 (HW=1024), L=4, NH=8, K=V=64.
// ---------------------------------------------------------------------------

typedef __attribute__((ext_vector_type(8))) short short8;
typedef __attribute__((ext_vector_type(4))) float f32x4;
typedef __attribute__((ext_vector_type(4))) unsigned short ushort4_t;

#define NTOK 65536   // B*HW*NH
#define NPIX 8192    // B*HW

__device__ __forceinline__ float bf2f(unsigned short u) {
  unsigned int v = ((unsigned int)u) << 16;
  float f; __builtin_memcpy(&f, &v, 4); return f;
}
__device__ __forceinline__ unsigned short f2bf(float f) {
  unsigned int u; __builtin_memcpy(&u, &f, 4);
  u = (u + 0x7FFFu + ((u >> 16) & 1u)) >> 16;
  return (unsigned short)u;
}

__device__ __forceinline__ void gl_lds16(const unsigned short* g, const unsigned short* l) {
  __builtin_amdgcn_global_load_lds(
      (const __attribute__((address_space(1))) unsigned int*)g,
      (__attribute__((address_space(3))) unsigned int*)l, 16, 0, 0);
}

// ---------------------------------------------------------------------------
// one-shot prep: all weight casts/reorders + bias concat
// wkqv [L][3][512][256]; w1 [1024][9][512]; w2 [1024][9][256]; biascat [L][3][512]
// ---------------------------------------------------------------------------
__global__ void k_prep(const float* __restrict__ kw, const float* __restrict__ vw,
                       const float* __restrict__ qw, const float* __restrict__ ow1,
                       const float* __restrict__ ow2, const float* __restrict__ kb,
                       const float* __restrict__ vb, const float* __restrict__ qb,
                       unsigned short* __restrict__ wkqv, unsigned short* __restrict__ w1,
                       unsigned short* __restrict__ w2, float* __restrict__ biascat) {
  long i = (long)blockIdx.x * 256 + threadIdx.x;
  if (i < 1572864) {
    int idx = (int)(i & 131071); int sl = (int)(i >> 17); int slot = sl % 3, l = sl / 3;
    const float* s = slot == 0 ? kw : slot == 1 ? vw : qw;
    wkqv[i] = f2bf(s[(size_t)l * 131072 + idx]);
    return;
  }
  i -= 1572864;
  if (i < 4718592) {
    int c = (int)(i % 512), tap = (int)((i / 512) % 9); long m = i / 4608;
    w1[i] = f2bf(ow1[(m * 512 + c) * 9 + tap]);
    return;
  }
  i -= 4718592;
  if (i < 2359296) {
    int c = (int)(i % 256), tap = (int)((i / 256) % 9); long m = i / 2304;
    w2[i] = f2bf(ow2[(m * 256 + c) * 9 + tap]);
    return;
  }
  i -= 2359296;
  if (i < 6144) {
    int o = (int)(i & 511); int sl = (int)(i >> 9); int slot = sl % 3, l = sl / 3;
    const float* s = slot == 0 ? kb : slot == 1 ? vb : qb;
    biascat[i] = s[l * 512 + o];
  }
}

// x (f32, [B][256][1024]) -> xcl (bf16, [B][1024][256])
__global__ __launch_bounds__(256) void k_x2cl(const float* __restrict__ src,
                                              unsigned short* __restrict__ dst) {
  __shared__ unsigned short t[64][68];
  const int hw0 = blockIdx.x * 64, b = blockIdx.y;
  const int tid = threadIdx.x;
  for (int cc = 0; cc < 4; cc++) {
    __syncthreads();
    {
      const int px = tid & 63, c = tid >> 6;
      #pragma unroll
      for (int i = 0; i < 16; i++)
        t[px][c + i * 4] = f2bf(src[((size_t)b * 256 + cc * 64 + c + i * 4) * 1024 + hw0 + px]);
    }
    __syncthreads();
    {
      const int px = tid >> 2, c0 = (tid & 3) * 16;
      unsigned short* dp = dst + ((size_t)b * 1024 + hw0 + px) * 256 + cc * 64 + c0;
      short8 v0, v1;
      #pragma unroll
      for (int i = 0; i < 8; i++) { v0[i] = (short)t[px][c0 + i]; v1[i] = (short)t[px][c0 + 8 + i]; }
      *(short8*)dp = v0; *(short8*)(dp + 8) = v1;
    }
  }
}

// ---------------------------------------------------------------------------
// MFMA GEMM v3: 128x128 tile, 4 waves (2x2 of 64x64, 4x4 frags each),
// K-step 64, double-buffered LDS via global_load_lds(16B), 1 barrier/step.
// XOR chunk swizzle: LDS (row, chunk) holds global k-chunk (chunk ^ (row&7)).
// MODE 0: QKV dense K=256, epi -> token-major k/v/q (+bias).
// MODE 1: conv1 CIN=512, split-K 4 (9 taps x 128-ch slices), epi -> partials.
// MODE 2: conv2 CIN=256, split-K 4 (9 taps x 64-ch slices),  epi -> partials.
// ---------------------------------------------------------------------------
template<int MODE, int NSTEP, int KDIM, int CIN>
__global__ __launch_bounds__(256) void k_gemm(
    const unsigned short* __restrict__ W,
    const unsigned short* __restrict__ act,
    const float* __restrict__ bias,
    int l,
    unsigned short* __restrict__ ktok, unsigned short* __restrict__ vtok,
    unsigned short* __restrict__ qtok,
    float* __restrict__ pout) {
  __shared__ unsigned short sm[2][2][8192];   // [buf][A/B][128 rows x 64 k]

  const int bid = blockIdx.x;
  int m0, b, pix0, s;
  if constexpr (MODE == 0) {
    const int xcd = bid & 7, li = bid >> 3;           // 96 per XCD
    const int nt = xcd * 8 + (li & 7);
    m0 = (li >> 3) * 128; s = 0;
    b = nt >> 3; pix0 = (nt & 7) * 128;
  } else {
    const int xcd = bid & 7, li = bid >> 3;           // 64 per XCD
    const int nt = xcd * 8 + (li & 7);
    const int r = li >> 3;                            // 0..7
    m0 = (r & 1) * 128; s = r >> 1;
    b = nt >> 3; pix0 = (nt & 7) * 128;
  }
  constexpr int SW = (MODE == 1) ? 128 : 64;          // split width in channels

  const int tid = threadIdx.x;
  const int wid = tid >> 6, lane = tid & 63;
  const int lr = lane & 15, lg = lane >> 4;
  const int m_off = (wid >> 1) * 64, n_off = (wid & 1) * 64;

  // per-lane staging bases (4 A-chunks + 4 B-chunks of 1KB per wave)
  const unsigned short* gA[4];
  const unsigned short* gB[4];
  #pragma unroll
  for (int j = 0; j < 4; j++) {
    const int o = (wid * 4 + j) * 512 + lane * 8;     // shorts into 16KB region
    const int row = o >> 6;                           // 0..127
    const int ksw = (((o >> 3) & 7) ^ (row & 7)) * 8; // swizzled k offset
    gA[j] = W + (size_t)(m0 + row) * KDIM + (MODE ? s * SW : 0) + ksw;
    if constexpr (MODE == 0) {
      gB[j] = act + ((size_t)b * 1024 + pix0 + row) * 256 + ksw;
    } else {
      const int pix = pix0 + row, py = pix >> 5, px = pix & 31;
      gB[j] = act + (size_t)b * 1156 * CIN + ((size_t)py * 34 + px) * CIN + s * SW + ksw;
    }
  }

  auto offA = [&](int st) -> int {
    if constexpr (MODE == 0) return st * 64;
    else if constexpr (MODE == 1) return (st >> 1) * 512 + (st & 1) * 64;
    else return st * 256;
  };
  auto offB = [&](int st) -> int {
    if constexpr (MODE == 0) return st * 64;
    else if constexpr (MODE == 1) {
      const int tap = st >> 1, dy = tap / 3, dx = tap - dy * 3;
      return (dy * 34 + dx) * 512 + (st & 1) * 64;
    } else {
      const int dy = st / 3, dx = st - dy * 3;
      return (dy * 34 + dx) * 256;
    }
  };
  auto STAGE = [&](int bf, int st) {
    const int oa = offA(st), ob = offB(st);
    #pragma unroll
    for (int j = 0; j < 4; j++) gl_lds16(gA[j] + oa, &sm[bf][0][(wid * 4 + j) * 512]);
    #pragma unroll
    for (int j = 0; j < 4; j++) gl_lds16(gB[j] + ob, &sm[bf][1][(wid * 4 + j) * 512]);
  };

  f32x4 acc[4][4] = {};

  STAGE(0, 0);
  __syncthreads();                       // vmcnt(0) drain + barrier
  #pragma unroll
  for (int st = 0; st < NSTEP; st++) {
    if (st + 1 < NSTEP) STAGE((st + 1) & 1, st + 1);
    const int cur = st & 1;
    #pragma unroll
    for (int ks = 0; ks < 2; ks++) {
      short8 af[4], bfr[4];
      #pragma unroll
      for (int i = 0; i < 4; i++) {
        const int ra = m_off + i * 16 + lr;
        af[i] = *(const short8*)&sm[cur][0][ra * 64 + (((ks * 4 + lg) ^ (ra & 7)) * 8)];
        const int rb = n_off + i * 16 + lr;
        bfr[i] = *(const short8*)&sm[cur][1][rb * 64 + (((ks * 4 + lg) ^ (rb & 7)) * 8)];
      }
      #pragma unroll
      for (int i = 0; i < 4; i++)
        #pragma unroll
        for (int jn = 0; jn < 4; jn++)
          acc[i][jn] = __builtin_amdgcn_mfma_f32_16x16x32_bf16(af[i], bfr[jn], acc[i][jn], 0, 0, 0);
    }
    __syncthreads();
  }

  // epilogue. D mapping: col = lane&15, row = (lane>>4)*4 + reg
  if constexpr (MODE == 0) {
    #pragma unroll
    for (int mi = 0; mi < 4; mi++) {
      const int mb = m0 + m_off + mi * 16 + lg * 4;
      const int tensor = mb >> 9, head = (mb >> 6) & 7, d0 = mb & 63;
      unsigned short* dst = (tensor == 0) ? ktok + (size_t)l * NTOK * 64
                          : (tensor == 1) ? vtok + (size_t)l * NTOK * 64 : qtok;
      const float b0 = bias[mb], b1 = bias[mb + 1], b2 = bias[mb + 2], b3 = bias[mb + 3];
      #pragma unroll
      for (int ni = 0; ni < 4; ni++) {
        const int n = pix0 + n_off + ni * 16 + lr;
        ushort4_t pk;
        pk[0] = f2bf(acc[mi][ni][0] + b0); pk[1] = f2bf(acc[mi][ni][1] + b1);
        pk[2] = f2bf(acc[mi][ni][2] + b2); pk[3] = f2bf(acc[mi][ni][3] + b3);
        *(ushort4_t*)&dst[(((size_t)b * 1024 + n) * 8 + head) * 64 + d0] = pk;
      }
    }
  } else {
    #pragma unroll
    for (int mi = 0; mi < 4; mi++) {
      const int mb = m0 + m_off + mi * 16 + lg * 4;
      float* orow = pout + (size_t)(s * 256 + mb) * 8192 + (size_t)b * 1024 + pix0;
      #pragma unroll
      for (int ni = 0; ni < 4; ni++) {
        const int n = n_off + ni * 16 + lr;
        #pragma unroll
        for (int r = 0; r < 4; r++) orow[(size_t)r * 8192 + n] = acc[mi][ni][r];
      }
    }
  }
}

// ---------------------------------------------------------------------------
// attention: 1 wave per token (lane = dim); writes opad (channel-last) interior
// ---------------------------------------------------------------------------
__global__ __launch_bounds__(256) void k_attn(const unsigned short* __restrict__ q_tok,
                                              const unsigned short* __restrict__ k_tok,
                                              const unsigned short* __restrict__ v_tok,
                                              unsigned short* __restrict__ opad, int l) {
  const int wid = threadIdx.x >> 6, lane = threadIdx.x & 63;
  const size_t token = (size_t)blockIdx.x * 4 + wid;
  const float qv = bf2f(q_tok[token * 64 + lane]) * 0.125f;
  float s[5];
  const int T = l + 2;
  for (int t = 0; t <= l; t++) {
    float p = qv * bf2f(k_tok[(size_t)t * NTOK * 64 + token * 64 + lane]);
    #pragma unroll
    for (int off = 32; off > 0; off >>= 1) p += __shfl_xor(p, off);
    s[t] = p;
  }
  s[l + 1] = 0.0f;
  float mx = s[0];
  for (int t = 1; t < T; t++) mx = fmaxf(mx, s[t]);
  float e[5], sum = 0.0f;
  for (int t = 0; t < T; t++) { e[t] = __expf(s[t] - mx); sum += e[t]; }
  const float inv = 1.0f / sum;
  float attn[5];
  for (int t = 0; t < T; t++) attn[t] = e[t] * inv;
  if (T == 5) {
    float a[5];
    #pragma unroll
    for (int t = 0; t < 5; t++) a[t] = attn[t];
    #pragma unroll
    for (int i = 0; i < 4; i++)
      #pragma unroll
      for (int j = 0; j < 4; j++)
        if (a[j] < a[j + 1]) { float tmp = a[j]; a[j] = a[j + 1]; a[j + 1] = tmp; }
    const float delta = a[3] + 1e-7f;
    float wsum = 0.0f;
    #pragma unroll
    for (int t = 0; t < 5; t++) { attn[t] = fmaxf(attn[t] - delta, 0.0f); wsum += attn[t]; }
    const float r = 1.0f / (wsum + 1e-7f);
    #pragma unroll
    for (int t = 0; t < 5; t++) attn[t] *= r;
  }
  float o = 0.0f;
  for (int t = 0; t <= l; t++) o += attn[t] * bf2f(v_tok[(size_t)t * NTOK * 64 + token * 64 + lane]);
  const int head = (int)(token & 7), pix = (int)(token >> 3);
  const int b = pix >> 10, hw = pix & 1023, y = hw >> 5, x = hw & 31;
  opad[((size_t)b * 1156 + (y + 1) * 34 + (x + 1)) * 512 + head * 64 + lane] = f2bf(o);
}

// ---------------------------------------------------------------------------
// conv1 combine: h1c[c][n] = sum_s p[s][c][n] + bias; fused BN train stats
// ---------------------------------------------------------------------------
__global__ __launch_bounds__(512) void k_comb_stats(const float* __restrict__ p,
    const float* __restrict__ bias1, const float* __restrict__ g, const float* __restrict__ bta,
    float* __restrict__ h1c, float* __restrict__ stats) {
  const int c = blockIdx.x, tid = threadIdx.x;
  const float bs = bias1[c];
  float s = 0.0f, ss = 0.0f;
  const float* p0 = p + (size_t)c * 8192;
  float* h0 = h1c + (size_t)c * 8192;
  for (int n = tid; n < 8192; n += 512) {
    float v = p0[n] + p0[n + 2097152] + p0[n + 4194304] + p0[n + 6291456] + bs;
    h0[n] = v; s += v; ss += v * v;
  }
  #pragma unroll
  for (int o = 32; o > 0; o >>= 1) { s += __shfl_xor(s, o); ss += __shfl_xor(ss, o); }
  __shared__ float rs[8], rss[8];
  const int wid = tid >> 6, lane = tid & 63;
  if (lane == 0) { rs[wid] = s; rss[wid] = ss; }
  __syncthreads();
  if (tid == 0) {
    float S = 0.0f, SS = 0.0f;
    #pragma unroll
    for (int w = 0; w < 8; w++) { S += rs[w]; SS += rss[w]; }
    const float m = S * (1.0f / 8192.0f);
    const float var = SS * (1.0f / 8192.0f) - m * m;
    const float A = g[c] * rsqrtf(var + 1e-5f);
    stats[c] = A;
    stats[256 + c] = bta[c] - m * A;
  }
}

// BN apply + ReLU -> padded channel-last bf16 [B][34*34][256] interior
__global__ __launch_bounds__(512) void k_bn_relu_pad(const float* __restrict__ h,
    const float* __restrict__ stats, unsigned short* __restrict__ hpad) {
  __shared__ unsigned short t[64][72];
  const int hw0 = blockIdx.x * 64, b = blockIdx.y, tid = threadIdx.x;
  for (int cc = 0; cc < 4; cc++) {
    __syncthreads();
    {
      const int px = tid & 63, c = tid >> 6;          // c in 0..7
      #pragma unroll
      for (int i = 0; i < 8; i++) {
        const int ch = cc * 64 + i * 8 + c;
        float v = h[(size_t)ch * 8192 + (size_t)b * 1024 + hw0 + px] * stats[ch] + stats[256 + ch];
        t[px][i * 8 + c] = f2bf(fmaxf(v, 0.0f));
      }
    }
    __syncthreads();
    {
      const int px = tid >> 3, c0 = (tid & 7) * 8;
      const int hw = hw0 + px, y = hw >> 5, x = hw & 31;
      short8 v;
      #pragma unroll
      for (int i = 0; i < 8; i++) v[i] = (short)t[px][c0 + i];
      *(short8*)&hpad[((size_t)b * 1156 + (y + 1) * 34 + (x + 1)) * 256 + cc * 64 + c0] = v;
    }
  }
}

// ---------------------------------------------------------------------------
// conv2 combine: xacc += gamma * (sum_s p + bias); also refresh xcl (bf16 CL)
// ---------------------------------------------------------------------------
__global__ __launch_bounds__(512) void k_comb2(const float* __restrict__ p,
    const float* __restrict__ bias2, const float* __restrict__ gamma_p, int last,
    float* __restrict__ xacc, unsigned short* __restrict__ xcl) {
  __shared__ unsigned short t[64][72];
  const int hw0 = blockIdx.x * 64, b = blockIdx.y, tid = threadIdx.x;
  const float g = gamma_p[0];
  for (int cc = 0; cc < 4; cc++) {
    __syncthreads();
    {
      const int px = tid & 63, c = tid >> 6;
      #pragma unroll
      for (int i = 0; i < 8; i++) {
        const int ch = cc * 64 + i * 8 + c;
        const size_t nb = (size_t)ch * 8192 + (size_t)b * 1024 + hw0 + px;
        float v = p[nb] + p[nb + 2097152] + p[nb + 4194304] + p[nb + 6291456] + bias2[ch];
        const size_t xi = ((size_t)b * 256 + ch) * 1024 + hw0 + px;
        const float xn = xacc[xi] + g * v;
        xacc[xi] = xn;
        t[px][i * 8 + c] = f2bf(xn);
      }
    }
    __syncthreads();
    if (!last) {
      const int px = tid >> 3, c0 = (tid & 7) * 8;
      short8 v;
      #pragma unroll
      for (int i = 0; i < 8; i++) v[i] = (short)t[px][c0 + i];
      *(short8*)&xcl[((size_t)b * 1024 + hw0 + px) * 256 + cc * 64 + c0] = v;
    }
  }
}

// ---------------------------------------------------------------------------
extern "C" void kernel_launch(void* const* d_in, const int* in_sizes, int n_in,
                              void* d_out, int out_size, void* d_ws, size_t ws_size,
                              hipStream_t stream) {
  (void)in_sizes; (void)n_in; (void)out_size;
  const float* x_in   = (const float*)d_in[0];
  const float* kw     = (const float*)d_in[1];
  const float* kb     = (const float*)d_in[2];
  const float* qw     = (const float*)d_in[3];
  const float* qb     = (const float*)d_in[4];
  const float* vw     = (const float*)d_in[5];
  const float* vb     = (const float*)d_in[6];
  const float* ow1    = (const float*)d_in[7];
  const float* ob1    = (const float*)d_in[8];
  const float* bn_g   = (const float*)d_in[9];
  const float* bn_b   = (const float*)d_in[10];
  const float* ow2    = (const float*)d_in[11];
  const float* ob2    = (const float*)d_in[12];
  const float* gammas = (const float*)d_in[13];

  char* ws = (char*)d_ws;
  size_t off = 0;
  auto alloc = [&](size_t bytes) -> void* {
    void* pp = ws + off;
    off += (bytes + 255) & ~(size_t)255;
    return pp;
  };
  unsigned short* xcl     = (unsigned short*)alloc((size_t)NPIX * 256 * 2);
  unsigned short* k_tok   = (unsigned short*)alloc((size_t)4 * NTOK * 64 * 2);
  unsigned short* v_tok   = (unsigned short*)alloc((size_t)4 * NTOK * 64 * 2);
  unsigned short* q_tok   = (unsigned short*)alloc((size_t)NTOK * 64 * 2);
  unsigned short* opad    = (unsigned short*)alloc((size_t)8 * 1156 * 512 * 2);
  float*          h1c     = (float*)alloc((size_t)256 * 8192 * 4);
  unsigned short* h1pad   = (unsigned short*)alloc((size_t)8 * 1156 * 256 * 2);
  float*          p1      = (float*)alloc((size_t)4 * 256 * 8192 * 4);   // split-K partials (reused)
  float*          stats   = (float*)alloc(512 * 4);
  unsigned short* wkqv    = (unsigned short*)alloc((size_t)4 * 3 * 512 * 256 * 2);
  unsigned short* w1bf    = (unsigned short*)alloc((size_t)1024 * 4608 * 2);
  unsigned short* w2bf    = (unsigned short*)alloc((size_t)1024 * 2304 * 2);
  float*          biascat = (float*)alloc((size_t)6144 * 4);
  if (off > ws_size) return;  // insufficient scratch — fail loudly at validation

  float* xacc = (float*)d_out;

  hipMemsetAsync(opad, 0, (size_t)8 * 1156 * 512 * 2, stream);
  hipMemsetAsync(h1pad, 0, (size_t)8 * 1156 * 256 * 2, stream);
  hipMemcpyAsync(xacc, x_in, (size_t)NPIX * 256 * 4, hipMemcpyDeviceToDevice, stream);
  k_prep<<<33816, 256, 0, stream>>>(kw, vw, qw, ow1, ow2, kb, vb, qb,
                                    wkqv, w1bf, w2bf, biascat);
  k_x2cl<<<dim3(16, 8), 256, 0, stream>>>(x_in, xcl);

  for (int l = 0; l < 4; l++) {
    // QKV: [1536][256] x [256 x 8192] -> token-major k/v/q
    k_gemm<0, 4, 256, 256><<<768, 256, 0, stream>>>(
        wkqv + (size_t)l * 3 * 512 * 256, xcl, biascat + l * 1536, l,
        k_tok, v_tok, q_tok, nullptr);
    k_attn<<<NTOK / 4, 256, 0, stream>>>(q_tok, k_tok, v_tok, opad, l);
    // conv3x3 #1: 512->256, K=4608, split-K 4 -> partials
    k_gemm<1, 18, 4608, 512><<<512, 256, 0, stream>>>(
        w1bf + (size_t)l * 256 * 4608, opad, nullptr, l,
        nullptr, nullptr, nullptr, p1);
    k_comb_stats<<<256, 512, 0, stream>>>(p1, ob1 + l * 256, bn_g + l * 256,
                                          bn_b + l * 256, h1c, stats);
    k_bn_relu_pad<<<dim3(16, 8), 512, 0, stream>>>(h1c, stats, h1pad);
    // conv3x3 #2: 256->256, K=2304, split-K 4 -> partials (p1 reused)
    k_gemm<2, 9, 2304, 256><<<512, 256, 0, stream>>>(
        w2bf + (size_t)l * 256 * 2304, h1pad, nullptr, l,
        nullptr, nullptr, nullptr, p1);
    k_comb2<<<dim3(16, 8), 512, 0, stream>>>(p1, ob2 + l * 256, gammas + l,
                                             (l == 3) ? 1 : 0, xacc, xcl);
  }
}

// Round 4
// 390.749 us; speedup vs baseline: 2.4295x; 1.2660x over previous
//
#include <hip/hip_runtime.h>

// ---------------------------------------------------------------------------
// AttentiveDensenet on MI355X (gfx950) — round 4: VALU-lean attention
// (4 lanes/token, quad-shuffle reduce, templated layer, pk-bf16 pack).
// GEMM path unchanged from round 3 (128x128 tiles, split-K, global_load_lds).
// B=8, C=256, H=W=32 (HW=1024), L=4, NH=8, K=V=64.
// ---------------------------------------------------------------------------

typedef __attribute__((ext_vector_type(8))) short short8;
typedef __attribute__((ext_vector_type(4))) float f32x4;
typedef __attribute__((ext_vector_type(4))) unsigned short ushort4_t;
typedef __attribute__((ext_vector_type(4))) unsigned int uint4_t;

#define NTOK 65536   // B*HW*NH
#define NPIX 8192    // B*HW

__device__ __forceinline__ float bf2f(unsigned short u) {
  unsigned int v = ((unsigned int)u) << 16;
  float f; __builtin_memcpy(&f, &v, 4); return f;
}
__device__ __forceinline__ unsigned short f2bf(float f) {
  unsigned int u; __builtin_memcpy(&u, &f, 4);
  u = (u + 0x7FFFu + ((u >> 16) & 1u)) >> 16;
  return (unsigned short)u;
}
__device__ __forceinline__ float blo(unsigned int u) {
  unsigned int v = u << 16; float f; __builtin_memcpy(&f, &v, 4); return f;
}
__device__ __forceinline__ float bhi(unsigned int u) {
  unsigned int v = u & 0xFFFF0000u; float f; __builtin_memcpy(&f, &v, 4); return f;
}

__device__ __forceinline__ void gl_lds16(const unsigned short* g, const unsigned short* l) {
  __builtin_amdgcn_global_load_lds(
      (const __attribute__((address_space(1))) unsigned int*)g,
      (__attribute__((address_space(3))) unsigned int*)l, 16, 0, 0);
}

// ---------------------------------------------------------------------------
// one-shot prep: all weight casts/reorders + bias concat
// ---------------------------------------------------------------------------
__global__ void k_prep(const float* __restrict__ kw, const float* __restrict__ vw,
                       const float* __restrict__ qw, const float* __restrict__ ow1,
                       const float* __restrict__ ow2, const float* __restrict__ kb,
                       const float* __restrict__ vb, const float* __restrict__ qb,
                       unsigned short* __restrict__ wkqv, unsigned short* __restrict__ w1,
                       unsigned short* __restrict__ w2, float* __restrict__ biascat) {
  long i = (long)blockIdx.x * 256 + threadIdx.x;
  if (i < 1572864) {
    int idx = (int)(i & 131071); int sl = (int)(i >> 17); int slot = sl % 3, l = sl / 3;
    const float* s = slot == 0 ? kw : slot == 1 ? vw : qw;
    wkqv[i] = f2bf(s[(size_t)l * 131072 + idx]);
    return;
  }
  i -= 1572864;
  if (i < 4718592) {
    int c = (int)(i % 512), tap = (int)((i / 512) % 9); long m = i / 4608;
    w1[i] = f2bf(ow1[(m * 512 + c) * 9 + tap]);
    return;
  }
  i -= 4718592;
  if (i < 2359296) {
    int c = (int)(i % 256), tap = (int)((i / 256) % 9); long m = i / 2304;
    w2[i] = f2bf(ow2[(m * 256 + c) * 9 + tap]);
    return;
  }
  i -= 2359296;
  if (i < 6144) {
    int o = (int)(i & 511); int sl = (int)(i >> 9); int slot = sl % 3, l = sl / 3;
    const float* s = slot == 0 ? kb : slot == 1 ? vb : qb;
    biascat[i] = s[l * 512 + o];
  }
}

// x (f32, [B][256][1024]) -> xcl (bf16, [B][1024][256])
__global__ __launch_bounds__(256) void k_x2cl(const float* __restrict__ src,
                                              unsigned short* __restrict__ dst) {
  __shared__ unsigned short t[64][68];
  const int hw0 = blockIdx.x * 64, b = blockIdx.y;
  const int tid = threadIdx.x;
  for (int cc = 0; cc < 4; cc++) {
    __syncthreads();
    {
      const int px = tid & 63, c = tid >> 6;
      #pragma unroll
      for (int i = 0; i < 16; i++)
        t[px][c + i * 4] = f2bf(src[((size_t)b * 256 + cc * 64 + c + i * 4) * 1024 + hw0 + px]);
    }
    __syncthreads();
    {
      const int px = tid >> 2, c0 = (tid & 3) * 16;
      unsigned short* dp = dst + ((size_t)b * 1024 + hw0 + px) * 256 + cc * 64 + c0;
      short8 v0, v1;
      #pragma unroll
      for (int i = 0; i < 8; i++) { v0[i] = (short)t[px][c0 + i]; v1[i] = (short)t[px][c0 + 8 + i]; }
      *(short8*)dp = v0; *(short8*)(dp + 8) = v1;
    }
  }
}

// ---------------------------------------------------------------------------
// MFMA GEMM v3 (unchanged from round 3)
// ---------------------------------------------------------------------------
template<int MODE, int NSTEP, int KDIM, int CIN>
__global__ __launch_bounds__(256) void k_gemm(
    const unsigned short* __restrict__ W,
    const unsigned short* __restrict__ act,
    const float* __restrict__ bias,
    int l,
    unsigned short* __restrict__ ktok, unsigned short* __restrict__ vtok,
    unsigned short* __restrict__ qtok,
    float* __restrict__ pout) {
  __shared__ unsigned short sm[2][2][8192];   // [buf][A/B][128 rows x 64 k]

  const int bid = blockIdx.x;
  int m0, b, pix0, s;
  if constexpr (MODE == 0) {
    const int xcd = bid & 7, li = bid >> 3;
    const int nt = xcd * 8 + (li & 7);
    m0 = (li >> 3) * 128; s = 0;
    b = nt >> 3; pix0 = (nt & 7) * 128;
  } else {
    const int xcd = bid & 7, li = bid >> 3;
    const int nt = xcd * 8 + (li & 7);
    const int r = li >> 3;
    m0 = (r & 1) * 128; s = r >> 1;
    b = nt >> 3; pix0 = (nt & 7) * 128;
  }
  constexpr int SW = (MODE == 1) ? 128 : 64;

  const int tid = threadIdx.x;
  const int wid = tid >> 6, lane = tid & 63;
  const int lr = lane & 15, lg = lane >> 4;
  const int m_off = (wid >> 1) * 64, n_off = (wid & 1) * 64;

  const unsigned short* gA[4];
  const unsigned short* gB[4];
  #pragma unroll
  for (int j = 0; j < 4; j++) {
    const int o = (wid * 4 + j) * 512 + lane * 8;
    const int row = o >> 6;
    const int ksw = (((o >> 3) & 7) ^ (row & 7)) * 8;
    gA[j] = W + (size_t)(m0 + row) * KDIM + (MODE ? s * SW : 0) + ksw;
    if constexpr (MODE == 0) {
      gB[j] = act + ((size_t)b * 1024 + pix0 + row) * 256 + ksw;
    } else {
      const int pix = pix0 + row, py = pix >> 5, px = pix & 31;
      gB[j] = act + (size_t)b * 1156 * CIN + ((size_t)py * 34 + px) * CIN + s * SW + ksw;
    }
  }

  auto offA = [&](int st) -> int {
    if constexpr (MODE == 0) return st * 64;
    else if constexpr (MODE == 1) return (st >> 1) * 512 + (st & 1) * 64;
    else return st * 256;
  };
  auto offB = [&](int st) -> int {
    if constexpr (MODE == 0) return st * 64;
    else if constexpr (MODE == 1) {
      const int tap = st >> 1, dy = tap / 3, dx = tap - dy * 3;
      return (dy * 34 + dx) * 512 + (st & 1) * 64;
    } else {
      const int dy = st / 3, dx = st - dy * 3;
      return (dy * 34 + dx) * 256;
    }
  };
  auto STAGE = [&](int bf, int st) {
    const int oa = offA(st), ob = offB(st);
    #pragma unroll
    for (int j = 0; j < 4; j++) gl_lds16(gA[j] + oa, &sm[bf][0][(wid * 4 + j) * 512]);
    #pragma unroll
    for (int j = 0; j < 4; j++) gl_lds16(gB[j] + ob, &sm[bf][1][(wid * 4 + j) * 512]);
  };

  f32x4 acc[4][4] = {};

  STAGE(0, 0);
  __syncthreads();
  #pragma unroll
  for (int st = 0; st < NSTEP; st++) {
    if (st + 1 < NSTEP) STAGE((st + 1) & 1, st + 1);
    const int cur = st & 1;
    #pragma unroll
    for (int ks = 0; ks < 2; ks++) {
      short8 af[4], bfr[4];
      #pragma unroll
      for (int i = 0; i < 4; i++) {
        const int ra = m_off + i * 16 + lr;
        af[i] = *(const short8*)&sm[cur][0][ra * 64 + (((ks * 4 + lg) ^ (ra & 7)) * 8)];
        const int rb = n_off + i * 16 + lr;
        bfr[i] = *(const short8*)&sm[cur][1][rb * 64 + (((ks * 4 + lg) ^ (rb & 7)) * 8)];
      }
      #pragma unroll
      for (int i = 0; i < 4; i++)
        #pragma unroll
        for (int jn = 0; jn < 4; jn++)
          acc[i][jn] = __builtin_amdgcn_mfma_f32_16x16x32_bf16(af[i], bfr[jn], acc[i][jn], 0, 0, 0);
    }
    __syncthreads();
  }

  if constexpr (MODE == 0) {
    #pragma unroll
    for (int mi = 0; mi < 4; mi++) {
      const int mb = m0 + m_off + mi * 16 + lg * 4;
      const int tensor = mb >> 9, head = (mb >> 6) & 7, d0 = mb & 63;
      unsigned short* dst = (tensor == 0) ? ktok + (size_t)l * NTOK * 64
                          : (tensor == 1) ? vtok + (size_t)l * NTOK * 64 : qtok;
      const float b0 = bias[mb], b1 = bias[mb + 1], b2 = bias[mb + 2], b3 = bias[mb + 3];
      #pragma unroll
      for (int ni = 0; ni < 4; ni++) {
        const int n = pix0 + n_off + ni * 16 + lr;
        ushort4_t pk;
        pk[0] = f2bf(acc[mi][ni][0] + b0); pk[1] = f2bf(acc[mi][ni][1] + b1);
        pk[2] = f2bf(acc[mi][ni][2] + b2); pk[3] = f2bf(acc[mi][ni][3] + b3);
        *(ushort4_t*)&dst[(((size_t)b * 1024 + n) * 8 + head) * 64 + d0] = pk;
      }
    }
  } else {
    #pragma unroll
    for (int mi = 0; mi < 4; mi++) {
      const int mb = m0 + m_off + mi * 16 + lg * 4;
      float* orow = pout + (size_t)(s * 256 + mb) * 8192 + (size_t)b * 1024 + pix0;
      #pragma unroll
      for (int ni = 0; ni < 4; ni++) {
        const int n = n_off + ni * 16 + lr;
        #pragma unroll
        for (int r = 0; r < 4; r++) orow[(size_t)r * 8192 + n] = acc[mi][ni][r];
      }
    }
  }
}

// ---------------------------------------------------------------------------
// attention v2: 4 lanes/token, 16 tokens/wave, 64 tokens/block, grid 1024.
// Buffers viewed as u32 (bf16 pairs). Templated on layer.
// ---------------------------------------------------------------------------
template<int L>
__global__ __launch_bounds__(256) void k_attn(const unsigned int* __restrict__ q_tok,
                                              const unsigned int* __restrict__ k_tok,
                                              const unsigned int* __restrict__ v_tok,
                                              unsigned int* __restrict__ opad) {
  constexpr int T = L + 2;                      // L+1 real entries + zero key
  const int lane = threadIdx.x & 63, wid = threadIdx.x >> 6;
  const int ti = lane >> 2, dq = lane & 3;
  const int token = blockIdx.x * 64 + wid * 16 + ti;
  const size_t rowq = (size_t)token * 32 + dq * 8;   // u32 units

  unsigned int q[8];
  *(uint4_t*)&q[0] = *(const uint4_t*)(q_tok + rowq);
  *(uint4_t*)&q[4] = *(const uint4_t*)(q_tok + rowq + 4);
  float qf[16];
  #pragma unroll
  for (int j = 0; j < 8; j++) {
    qf[2 * j]     = blo(q[j]) * 0.125f;        // q / sqrt(K)
    qf[2 * j + 1] = bhi(q[j]) * 0.125f;
  }

  float s[T];
  s[T - 1] = 0.0f;                              // zero-key score
  #pragma unroll
  for (int t = 0; t <= L; t++) {
    const unsigned int* kp = k_tok + (size_t)t * (NTOK * 32) + rowq;
    unsigned int kk[8];
    *(uint4_t*)&kk[0] = *(const uint4_t*)kp;
    *(uint4_t*)&kk[4] = *(const uint4_t*)(kp + 4);
    float p = 0.0f;
    #pragma unroll
    for (int j = 0; j < 8; j++) {
      p = fmaf(qf[2 * j], blo(kk[j]), p);
      p = fmaf(qf[2 * j + 1], bhi(kk[j]), p);
    }
    p += __shfl_xor(p, 1);                      // quad reduce (4 lanes span 64 dims)
    p += __shfl_xor(p, 2);
    s[t] = p;
  }

  float mx = s[0];
  #pragma unroll
  for (int t = 1; t < T; t++) mx = fmaxf(mx, s[t]);
  float attn[T], sum = 0.0f;
  #pragma unroll
  for (int t = 0; t < T; t++) { attn[t] = __expf(s[t] - mx); sum += attn[t]; }
  const float inv = 1.0f / sum;
  #pragma unroll
  for (int t = 0; t < T; t++) attn[t] *= inv;

  if constexpr (T == 5) {                       // top-4 of 5: delta = 2nd-smallest
    float m1 = attn[0], m2 = 1e30f;
    #pragma unroll
    for (int t = 1; t < 5; t++) {
      const float a = attn[t];
      const float nm1 = fminf(m1, a);
      m2 = fminf(m2, fmaxf(m1, a));
      m1 = nm1;
    }
    const float delta = m2 + 1e-7f;
    float ws = 0.0f;
    #pragma unroll
    for (int t = 0; t < 5; t++) { attn[t] = fmaxf(attn[t] - delta, 0.0f); ws += attn[t]; }
    const float r = 1.0f / (ws + 1e-7f);
    #pragma unroll
    for (int t = 0; t < 5; t++) attn[t] *= r;
  }

  float o[16];
  #pragma unroll
  for (int i = 0; i < 16; i++) o[i] = 0.0f;
  #pragma unroll
  for (int t = 0; t <= L; t++) {
    const unsigned int* vp = v_tok + (size_t)t * (NTOK * 32) + rowq;
    unsigned int vv[8];
    *(uint4_t*)&vv[0] = *(const uint4_t*)vp;
    *(uint4_t*)&vv[4] = *(const uint4_t*)(vp + 4);
    const float a = attn[t];
    #pragma unroll
    for (int j = 0; j < 8; j++) {
      o[2 * j]     = fmaf(a, blo(vv[j]), o[2 * j]);
      o[2 * j + 1] = fmaf(a, bhi(vv[j]), o[2 * j + 1]);
    }
  }

  unsigned int po[8];
  #pragma unroll
  for (int j = 0; j < 8; j++) {
    unsigned int r;
    asm("v_cvt_pk_bf16_f32 %0, %1, %2" : "=v"(r) : "v"(o[2 * j]), "v"(o[2 * j + 1]));
    po[j] = r;
  }
  const int head = token & 7, pix = token >> 3;
  const int b = pix >> 10, hw = pix & 1023, y = hw >> 5, x = hw & 31;
  unsigned int* dp = opad +
      (((size_t)b * 1156 + (y + 1) * 34 + (x + 1)) * 512 + head * 64 + dq * 16) / 2;
  *(uint4_t*)dp = *(uint4_t*)&po[0];
  *(uint4_t*)(dp + 4) = *(uint4_t*)&po[4];
}

// ---------------------------------------------------------------------------
// conv1 combine + fused BN train stats (unchanged)
// ---------------------------------------------------------------------------
__global__ __launch_bounds__(512) void k_comb_stats(const float* __restrict__ p,
    const float* __restrict__ bias1, const float* __restrict__ g, const float* __restrict__ bta,
    float* __restrict__ h1c, float* __restrict__ stats) {
  const int c = blockIdx.x, tid = threadIdx.x;
  const float bs = bias1[c];
  float s = 0.0f, ss = 0.0f;
  const float* p0 = p + (size_t)c * 8192;
  float* h0 = h1c + (size_t)c * 8192;
  for (int n = tid; n < 8192; n += 512) {
    float v = p0[n] + p0[n + 2097152] + p0[n + 4194304] + p0[n + 6291456] + bs;
    h0[n] = v; s += v; ss += v * v;
  }
  #pragma unroll
  for (int o = 32; o > 0; o >>= 1) { s += __shfl_xor(s, o); ss += __shfl_xor(ss, o); }
  __shared__ float rs[8], rss[8];
  const int wid = tid >> 6, lane = tid & 63;
  if (lane == 0) { rs[wid] = s; rss[wid] = ss; }
  __syncthreads();
  if (tid == 0) {
    float S = 0.0f, SS = 0.0f;
    #pragma unroll
    for (int w = 0; w < 8; w++) { S += rs[w]; SS += rss[w]; }
    const float m = S * (1.0f / 8192.0f);
    const float var = SS * (1.0f / 8192.0f) - m * m;
    const float A = g[c] * rsqrtf(var + 1e-5f);
    stats[c] = A;
    stats[256 + c] = bta[c] - m * A;
  }
}

// BN apply + ReLU -> padded channel-last bf16 [B][34*34][256] interior
__global__ __launch_bounds__(512) void k_bn_relu_pad(const float* __restrict__ h,
    const float* __restrict__ stats, unsigned short* __restrict__ hpad) {
  __shared__ unsigned short t[64][72];
  const int hw0 = blockIdx.x * 64, b = blockIdx.y, tid = threadIdx.x;
  for (int cc = 0; cc < 4; cc++) {
    __syncthreads();
    {
      const int px = tid & 63, c = tid >> 6;
      #pragma unroll
      for (int i = 0; i < 8; i++) {
        const int ch = cc * 64 + i * 8 + c;
        float v = h[(size_t)ch * 8192 + (size_t)b * 1024 + hw0 + px] * stats[ch] + stats[256 + ch];
        t[px][i * 8 + c] = f2bf(fmaxf(v, 0.0f));
      }
    }
    __syncthreads();
    {
      const int px = tid >> 3, c0 = (tid & 7) * 8;
      const int hw = hw0 + px, y = hw >> 5, x = hw & 31;
      short8 v;
      #pragma unroll
      for (int i = 0; i < 8; i++) v[i] = (short)t[px][c0 + i];
      *(short8*)&hpad[((size_t)b * 1156 + (y + 1) * 34 + (x + 1)) * 256 + cc * 64 + c0] = v;
    }
  }
}

// conv2 combine: xacc += gamma * (sum_s p + bias); refresh xcl
__global__ __launch_bounds__(512) void k_comb2(const float* __restrict__ p,
    const float* __restrict__ bias2, const float* __restrict__ gamma_p, int last,
    float* __restrict__ xacc, unsigned short* __restrict__ xcl) {
  __shared__ unsigned short t[64][72];
  const int hw0 = blockIdx.x * 64, b = blockIdx.y, tid = threadIdx.x;
  const float g = gamma_p[0];
  for (int cc = 0; cc < 4; cc++) {
    __syncthreads();
    {
      const int px = tid & 63, c = tid >> 6;
      #pragma unroll
      for (int i = 0; i < 8; i++) {
        const int ch = cc * 64 + i * 8 + c;
        const size_t nb = (size_t)ch * 8192 + (size_t)b * 1024 + hw0 + px;
        float v = p[nb] + p[nb + 2097152] + p[nb + 4194304] + p[nb + 6291456] + bias2[ch];
        const size_t xi = ((size_t)b * 256 + ch) * 1024 + hw0 + px;
        const float xn = xacc[xi] + g * v;
        xacc[xi] = xn;
        t[px][i * 8 + c] = f2bf(xn);
      }
    }
    __syncthreads();
    if (!last) {
      const int px = tid >> 3, c0 = (tid & 7) * 8;
      short8 v;
      #pragma unroll
      for (int i = 0; i < 8; i++) v[i] = (short)t[px][c0 + i];
      *(short8*)&xcl[((size_t)b * 1024 + hw0 + px) * 256 + cc * 64 + c0] = v;
    }
  }
}

// ---------------------------------------------------------------------------
extern "C" void kernel_launch(void* const* d_in, const int* in_sizes, int n_in,
                              void* d_out, int out_size, void* d_ws, size_t ws_size,
                              hipStream_t stream) {
  (void)in_sizes; (void)n_in; (void)out_size;
  const float* x_in   = (const float*)d_in[0];
  const float* kw     = (const float*)d_in[1];
  const float* kb     = (const float*)d_in[2];
  const float* qw     = (const float*)d_in[3];
  const float* qb     = (const float*)d_in[4];
  const float* vw     = (const float*)d_in[5];
  const float* vb     = (const float*)d_in[6];
  const float* ow1    = (const float*)d_in[7];
  const float* ob1    = (const float*)d_in[8];
  const float* bn_g   = (const float*)d_in[9];
  const float* bn_b   = (const float*)d_in[10];
  const float* ow2    = (const float*)d_in[11];
  const float* ob2    = (const float*)d_in[12];
  const float* gammas = (const float*)d_in[13];

  char* ws = (char*)d_ws;
  size_t off = 0;
  auto alloc = [&](size_t bytes) -> void* {
    void* pp = ws + off;
    off += (bytes + 255) & ~(size_t)255;
    return pp;
  };
  unsigned short* xcl     = (unsigned short*)alloc((size_t)NPIX * 256 * 2);
  unsigned short* k_tok   = (unsigned short*)alloc((size_t)4 * NTOK * 64 * 2);
  unsigned short* v_tok   = (unsigned short*)alloc((size_t)4 * NTOK * 64 * 2);
  unsigned short* q_tok   = (unsigned short*)alloc((size_t)NTOK * 64 * 2);
  unsigned short* opad    = (unsigned short*)alloc((size_t)8 * 1156 * 512 * 2);
  float*          h1c     = (float*)alloc((size_t)256 * 8192 * 4);
  unsigned short* h1pad   = (unsigned short*)alloc((size_t)8 * 1156 * 256 * 2);
  float*          p1      = (float*)alloc((size_t)4 * 256 * 8192 * 4);
  float*          stats   = (float*)alloc(512 * 4);
  unsigned short* wkqv    = (unsigned short*)alloc((size_t)4 * 3 * 512 * 256 * 2);
  unsigned short* w1bf    = (unsigned short*)alloc((size_t)1024 * 4608 * 2);
  unsigned short* w2bf    = (unsigned short*)alloc((size_t)1024 * 2304 * 2);
  float*          biascat = (float*)alloc((size_t)6144 * 4);
  if (off > ws_size) return;

  float* xacc = (float*)d_out;

  hipMemsetAsync(opad, 0, (size_t)8 * 1156 * 512 * 2, stream);
  hipMemsetAsync(h1pad, 0, (size_t)8 * 1156 * 256 * 2, stream);
  hipMemcpyAsync(xacc, x_in, (size_t)NPIX * 256 * 4, hipMemcpyDeviceToDevice, stream);
  k_prep<<<33816, 256, 0, stream>>>(kw, vw, qw, ow1, ow2, kb, vb, qb,
                                    wkqv, w1bf, w2bf, biascat);
  k_x2cl<<<dim3(16, 8), 256, 0, stream>>>(x_in, xcl);

  for (int l = 0; l < 4; l++) {
    k_gemm<0, 4, 256, 256><<<768, 256, 0, stream>>>(
        wkqv + (size_t)l * 3 * 512 * 256, xcl, biascat + l * 1536, l,
        k_tok, v_tok, q_tok, nullptr);
    const unsigned int* qt = (const unsigned int*)q_tok;
    const unsigned int* kt = (const unsigned int*)k_tok;
    const unsigned int* vt = (const unsigned int*)v_tok;
    unsigned int* op = (unsigned int*)opad;
    switch (l) {
      case 0: k_attn<0><<<1024, 256, 0, stream>>>(qt, kt, vt, op); break;
      case 1: k_attn<1><<<1024, 256, 0, stream>>>(qt, kt, vt, op); break;
      case 2: k_attn<2><<<1024, 256, 0, stream>>>(qt, kt, vt, op); break;
      default: k_attn<3><<<1024, 256, 0, stream>>>(qt, kt, vt, op); break;
    }
    k_gemm<1, 18, 4608, 512><<<512, 256, 0, stream>>>(
        w1bf + (size_t)l * 256 * 4608, opad, nullptr, l,
        nullptr, nullptr, nullptr, p1);
    k_comb_stats<<<256, 512, 0, stream>>>(p1, ob1 + l * 256, bn_g + l * 256,
                                          bn_b + l * 256, h1c, stats);
    k_bn_relu_pad<<<dim3(16, 8), 512, 0, stream>>>(h1c, stats, h1pad);
    k_gemm<2, 9, 2304, 256><<<512, 256, 0, stream>>>(
        w2bf + (size_t)l * 256 * 2304, h1pad, nullptr, l,
        nullptr, nullptr, nullptr, p1);
    k_comb2<<<dim3(16, 8), 512, 0, stream>>>(p1, ob2 + l * 256, gammas + l,
                                             (l == 3) ? 1 : 0, xacc, xcl);
  }
}